// Round 6
// baseline (58.466 us; speedup 1.0000x reference)
//
#include <hip/hip_runtime.h>

#define D8      8
#define LPATH   2048
#define NBATCH  64
#define NSTEPS  2047         // L-1 increments
#define NCHUNK  32
#define CSTEPS  64           // increments per chunk (last chunk: 63)
#define SIGLEN  4680         // 8 + 64 + 512 + 4096
#define OFF2    8
#define OFF3    72
#define OFF4    584
// Intermediate (workspace) sig layout is TRANSPOSED for coalescing:
//   L1 m            -> m
//   L2 (a,b)        -> OFF2 + a*8+b          (lane-indexed, coalesced)
//   L3 (a,b,c)      -> OFF3 + c*64 + a*8+b
//   L4 (a,b,c,d)    -> OFF4 + (c*8+d)*64 + a*8+b
// d_out uses the canonical reference layout (written only by the last fold).

__device__ __forceinline__ void load8(const float* __restrict__ p, float* v) {
    float4 a = ((const float4*)p)[0];
    float4 b = ((const float4*)p)[1];
    v[0]=a.x; v[1]=a.y; v[2]=a.z; v[3]=a.w;
    v[4]=b.x; v[5]=b.y; v[6]=b.z; v[7]=b.w;
}
__device__ __forceinline__ void store8(float* __restrict__ p, const float* v) {
    ((float4*)p)[0] = make_float4(v[0],v[1],v[2],v[3]);
    ((float4*)p)[1] = make_float4(v[4],v[5],v[6],v[7]);
}

// ============================ Phase 1 ============================
// Block = 256 threads = 4 waves per chunk; wave w owns k rows {2w, 2w+1}.
// Increments z[s][:] in LDS (coalesced prologue); step loop is LDS+VALU only.
// Per-thread state ~50 floats -> stays in arch VGPRs (no AGPR churn).

__device__ __forceinline__ void zload(const float* __restrict__ zl, int s, int i, int j,
                                      float (&Z)[8], float& Zi, float& Zj) {
    const float4* z4 = (const float4*)zl;
    float4 a = z4[2 * s], b = z4[2 * s + 1];
    Z[0]=a.x; Z[1]=a.y; Z[2]=a.z; Z[3]=a.w;
    Z[4]=b.x; Z[5]=b.y; Z[6]=b.z; Z[7]=b.w;
    Zi = zl[s * 8 + i];   // 8 addrs x 8-lane broadcast, conflict-free
    Zj = zl[s * 8 + j];
}

template<int KB>
__device__ __forceinline__ void sig_step(const float (&Z)[8], float Zi, float Zj,
                                         float (&A4)[2][8], float (&a3)[2],
                                         float& A2, float& a1i) {
    const float p  = Zi * Zj;
    const float uq = a1i * Zj;
    const float c4 = fmaf(uq, 1.f/6.f, fmaf(p, 1.f/24.f, A2 * 0.5f));
    const float c3 = fmaf(uq, 0.5f,    fmaf(p, 1.f/6.f,  A2));
#pragma unroll
    for (int kk = 0; kk < 2; ++kk) {
        const float zk = Z[KB + kk];                 // compile-time index
        const float f  = fmaf(c4, zk, a3[kk]);
#pragma unroll
        for (int l = 0; l < 8; ++l) A4[kk][l] = fmaf(f, Z[l], A4[kk][l]);
        a3[kk] = fmaf(c3, zk, a3[kk]);
    }
    A2 = A2 + fmaf(p, 0.5f, uq);
    a1i += Zi;
}

template<int KB>
__device__ __forceinline__ void chunk_body(const float* __restrict__ zl,
                                           const float* __restrict__ pb,
                                           float* __restrict__ o,
                                           int t0, int t1, int n,
                                           int lane, int i, int j) {
    float A4[2][8], a3[2];
    float A2 = 0.f, a1i = 0.f;
#pragma unroll
    for (int kk = 0; kk < 2; ++kk) {
        a3[kk] = 0.f;
#pragma unroll
        for (int l = 0; l < 8; ++l) A4[kk][l] = 0.f;
    }

    float ZA[8], ZB[8];
    float ZAi, ZAj, ZBi, ZBj;
    zload(zl, 0, i, j, ZA, ZAi, ZAj);

    int s = 0;
    for (; s + 1 < n; s += 2) {
        zload(zl, s + 1, i, j, ZB, ZBi, ZBj);
        sig_step<KB>(ZA, ZAi, ZAj, A4, a3, A2, a1i);
        const int s2 = (s + 2 < n) ? (s + 2) : (n - 1);   // clamped junk prefetch
        zload(zl, s2, i, j, ZA, ZAi, ZAj);
        sig_step<KB>(ZB, ZBi, ZBj, A4, a3, A2, a1i);
    }
    if (s < n) sig_step<KB>(ZA, ZAi, ZAj, A4, a3, A2, a1i);  // odd tail (n=63)

    if (KB == 0) {
        if (lane < 8) o[lane] = pb[(size_t)t1 * D8 + lane] - pb[(size_t)t0 * D8 + lane];
        o[OFF2 + lane] = A2;
    }
#pragma unroll
    for (int kk = 0; kk < 2; ++kk) {
        o[OFF3 + (KB + kk) * 64 + lane] = a3[kk];            // coalesced
#pragma unroll
        for (int l = 0; l < 8; ++l)
            o[OFF4 + ((KB + kk) * 8 + l) * 64 + lane] = A4[kk][l];  // coalesced
    }
}

__global__ __launch_bounds__(256) void sig_chunk_kernel(const float* __restrict__ path,
                                                        float* __restrict__ sigs) {
    __shared__ float4 zl4[130];                   // 64 steps x 8 floats (+pad)
    float* zl = (float*)zl4;

    const int wg   = blockIdx.x;                  // b*NCHUNK + c
    const int b    = wg >> 5;
    const int c    = wg & (NCHUNK - 1);
    const int tid  = threadIdx.x;
    const int w    = tid >> 6;
    const int lane = tid & 63;
    const int i    = lane >> 3;
    const int j    = lane & 7;
    const int t0   = c * CSTEPS;
    const int t1   = (t0 + CSTEPS < NSTEPS) ? (t0 + CSTEPS) : NSTEPS;
    const int n    = t1 - t0;                     // 64 or 63
    const float* __restrict__ pb = path + (size_t)b * LPATH * D8;

    // prologue: z[s][m] = p[t0+s+1][m] - p[t0+s][m], one float4 per thread (tid<128)
    if (tid * 4 < n * 8) {
        const float* src = pb + (size_t)t0 * D8 + tid * 4;
        float4 a  = *(const float4*)(src + 8);
        float4 bq = *(const float4*)(src);
        zl4[tid] = make_float4(a.x - bq.x, a.y - bq.y, a.z - bq.z, a.w - bq.w);
    }
    __syncthreads();

    float* __restrict__ o = sigs + (size_t)wg * SIGLEN;
    if      (w == 0) chunk_body<0>(zl, pb, o, t0, t1, n, lane, i, j);
    else if (w == 1) chunk_body<2>(zl, pb, o, t0, t1, n, lane, i, j);
    else if (w == 2) chunk_body<4>(zl, pb, o, t0, t1, n, lane, i, j);
    else             chunk_body<6>(zl, pb, o, t0, t1, n, lane, i, j);
}

// ============================ Phase 2 ============================
// k-split Chen combine over transposed sigs; all big loads coalesced dwords.
// 1 block = 4 waves per group; wave w owns k rows {2w,2w+1}.

template<int NPER, bool CANON_OUT>
__global__ __launch_bounds__(256) void sig_combine_kernel(const float* __restrict__ in,
                                                          float* __restrict__ out) {
    const int grp  = blockIdx.x;
    const int tid  = threadIdx.x;
    const int w    = tid >> 6;
    const int lane = tid & 63;
    const int i    = lane >> 3;
    const int j    = lane & 7;
    const int k0   = 2 * w;
    const float* __restrict__ base = in + (size_t)grp * NPER * SIGLEN;

    float A4[2][8], a3[2], A1[8], A2, a1i;
    load8(base, A1);
    a1i = base[i];
    A2  = base[OFF2 + lane];
    a3[0] = base[OFF3 + k0 * 64 + lane];
    a3[1] = base[OFF3 + (k0 + 1) * 64 + lane];
#pragma unroll
    for (int kk = 0; kk < 2; ++kk)
#pragma unroll
        for (int l = 0; l < 8; ++l)
            A4[kk][l] = base[OFF4 + ((k0 + kk) * 8 + l) * 64 + lane];

#pragma unroll 2
    for (int s = 1; s < NPER; ++s) {
        const float* __restrict__ B = base + (size_t)s * SIGLEN;
        float B1[8];   load8(B, B1);
        const float b1i = B[i];
        const float b1j = B[j];
        const float b2t = B[OFF2 + lane];                    // coalesced
        const float b1k[2]  = { B[k0], B[k0 + 1] };
        const float b3k[2]  = { B[OFF3 + k0 * 64 + lane],    // coalesced
                                B[OFF3 + (k0 + 1) * 64 + lane] };
        const float b2jk[2] = { B[OFF2 + j * 8 + k0],
                                B[OFF2 + j * 8 + k0 + 1] };
        float b4r[2][8], b2r[2][8], b3r[2][8];
#pragma unroll
        for (int kk = 0; kk < 2; ++kk) {
#pragma unroll
            for (int l = 0; l < 8; ++l)
                b4r[kk][l] = B[OFF4 + ((k0 + kk) * 8 + l) * 64 + lane];  // coalesced
            load8(B + OFF2 + (k0 + kk) * 8, b2r[kk]);        // uniform
#pragma unroll
            for (int l = 0; l < 8; ++l)
                b3r[kk][l] = B[OFF3 + l * 64 + j * 8 + (k0 + kk)];       // bcast groups
        }
        // C4[i,j,k,l] = A4 + B4 + A3[k]*B1[l] + A2*B2[k,l] + A1[i]*B3[j,k,l]
#pragma unroll
        for (int kk = 0; kk < 2; ++kk) {
#pragma unroll
            for (int l = 0; l < 8; ++l) {
                float v = A4[kk][l] + b4r[kk][l];
                v = fmaf(a3[kk], B1[l], v);
                v = fmaf(A2,     b2r[kk][l], v);
                A4[kk][l] = fmaf(a1i, b3r[kk][l], v);
            }
        }
        // C3[i,j,k] = A3 + B3[i,j,k] + A2*B1[k] + A1[i]*B2[j,k]
        a3[0] = fmaf(a1i, b2jk[0], fmaf(A2, b1k[0], a3[0] + b3k[0]));
        a3[1] = fmaf(a1i, b2jk[1], fmaf(A2, b1k[1], a3[1] + b3k[1]));
        // C2, C1
        A2 = A2 + fmaf(a1i, b1j, b2t);
#pragma unroll
        for (int m = 0; m < 8; ++m) A1[m] += B1[m];
        a1i += b1i;
    }

    float* __restrict__ o = out + (size_t)grp * SIGLEN;
    if (w == 0) {
        if (lane < 8) o[lane] = A1[lane];
        o[OFF2 + lane] = A2;
    }
    if (CANON_OUT) {
        o[OFF3 + lane * 8 + k0]     = a3[0];
        o[OFF3 + lane * 8 + k0 + 1] = a3[1];
        store8(o + OFF4 + lane * 64 + k0 * 8,       A4[0]);
        store8(o + OFF4 + lane * 64 + (k0 + 1) * 8, A4[1]);
    } else {
        o[OFF3 + k0 * 64 + lane]       = a3[0];
        o[OFF3 + (k0 + 1) * 64 + lane] = a3[1];
#pragma unroll
        for (int kk = 0; kk < 2; ++kk)
#pragma unroll
            for (int l = 0; l < 8; ++l)
                o[OFF4 + ((k0 + kk) * 8 + l) * 64 + lane] = A4[kk][l];
    }
}

extern "C" void kernel_launch(void* const* d_in, const int* in_sizes, int n_in,
                              void* d_out, int out_size, void* d_ws, size_t ws_size,
                              hipStream_t stream) {
    const float* path = (const float*)d_in[0];
    float* out   = (float*)d_out;
    float* sigs  = (float*)d_ws;                                  // 64*32*4680 f32 = 38.3 MB
    float* gsigs = sigs + (size_t)NBATCH * NCHUNK * SIGLEN;       // 64*4*4680 f32 = 4.8 MB

    sig_chunk_kernel<<<NBATCH * NCHUNK, 256, 0, stream>>>(path, sigs);
    sig_combine_kernel<8, false><<<NBATCH * 4, 256, 0, stream>>>(sigs, gsigs);
    sig_combine_kernel<4, true><<<NBATCH, 256, 0, stream>>>(gsigs, out);
}

// Round 7
// 54.046 us; speedup vs baseline: 1.0818x; 1.0818x over previous
//
#include <hip/hip_runtime.h>

#define D8      8
#define LPATH   2048
#define NBATCH  64
#define NSTEPS  2047         // L-1 increments
#define NCHUNK  32
#define CSTEPS  64           // increments per chunk (last chunk: 63)
#define SIGLEN  4680         // 8 + 64 + 512 + 4096
#define OFF2    8
#define OFF3    72
#define OFF4    584
// Workspace sig layout is TRANSPOSED for coalescing:
//   L1 m         -> m
//   L2 (a,b)     -> OFF2 + a*8+b                (lane-indexed)
//   L3 (a,b,c)   -> OFF3 + c*64 + (a*8+b)
//   L4 (a,b,c,d) -> OFF4 + (c*8+d)*64 + (a*8+b)
// d_out uses the canonical reference layout (written only by the last fold).

__device__ __forceinline__ void load8(const float* __restrict__ p, float* v) {
    float4 a = ((const float4*)p)[0];
    float4 b = ((const float4*)p)[1];
    v[0]=a.x; v[1]=a.y; v[2]=a.z; v[3]=a.w;
    v[4]=b.x; v[5]=b.y; v[6]=b.z; v[7]=b.w;
}
__device__ __forceinline__ void store8(float* __restrict__ p, const float* v) {
    ((float4*)p)[0] = make_float4(v[0],v[1],v[2],v[3]);
    ((float4*)p)[1] = make_float4(v[4],v[5],v[6],v[7]);
}

// ============================ Phase 1 ============================
// Block = 128 threads = 2 waves per chunk; wave w owns k in [4w,4w+4).
// Increments z[s][:] precomputed into LDS by a coalesced prologue; the hot
// loop is LDS+VALU only, with a 3-buffer Z rotation (prefetch distance ~2.7
// steps ≈ 300 cyc > LDS latency, robust to compiler load placement).

__device__ __forceinline__ void zload(const float* __restrict__ zl, int s, int i, int j,
                                      float (&Z)[8], float& Zi, float& Zj) {
    const float4* z4 = (const float4*)zl;
    float4 a = z4[2 * s], b = z4[2 * s + 1];
    Z[0]=a.x; Z[1]=a.y; Z[2]=a.z; Z[3]=a.w;
    Z[4]=b.x; Z[5]=b.y; Z[6]=b.z; Z[7]=b.w;
    Zi = zl[s * 8 + i];   // 8 addrs x 8-lane broadcast, conflict-free
    Zj = zl[s * 8 + j];
}

template<int KB>
__device__ __forceinline__ void sig_step(const float (&Z)[8], float Zi, float Zj,
                                         float (&A4)[4][8], float (&A3)[4],
                                         float& A2, float& a1i) {
    const float p  = Zi * Zj;
    const float uq = a1i * Zj;
    const float c4 = fmaf(uq, 1.f/6.f, fmaf(p, 1.f/24.f, A2 * 0.5f));
    const float c3 = fmaf(uq, 0.5f,    fmaf(p, 1.f/6.f,  A2));
#pragma unroll
    for (int kk = 0; kk < 4; ++kk) {
        const float zk = Z[KB + kk];                 // compile-time index
        const float f  = fmaf(c4, zk, A3[kk]);
#pragma unroll
        for (int l = 0; l < 8; ++l) A4[kk][l] = fmaf(f, Z[l], A4[kk][l]);
        A3[kk] = fmaf(c3, zk, A3[kk]);
    }
    A2 = A2 + fmaf(p, 0.5f, uq);
    a1i += Zi;
}

template<int KB>
__device__ __forceinline__ void chunk_body(const float* __restrict__ zl,
                                           const float* __restrict__ pb,
                                           float* __restrict__ o,
                                           int t0, int t1, int n,
                                           int lane, int i, int j) {
    float A4[4][8], A3[4];
    float A2 = 0.f, a1i = 0.f;
#pragma unroll
    for (int kk = 0; kk < 4; ++kk) {
        A3[kk] = 0.f;
#pragma unroll
        for (int l = 0; l < 8; ++l) A4[kk][l] = 0.f;
    }

    float ZA[8], ZB[8], ZC[8];
    float ZAi, ZAj, ZBi, ZBj, ZCi, ZCj;
    zload(zl, 0, i, j, ZA, ZAi, ZAj);
    { const int s1 = (1 < n) ? 1 : (n - 1); zload(zl, s1, i, j, ZB, ZBi, ZBj); }
    { const int s2 = (2 < n) ? 2 : (n - 1); zload(zl, s2, i, j, ZC, ZCi, ZCj); }

    const int triples = n / 3;
    int s = 0;
    for (int r = 0; r < triples; ++r) {
        sig_step<KB>(ZA, ZAi, ZAj, A4, A3, A2, a1i);
        { const int sa = (s + 3 < n) ? (s + 3) : (n - 1); zload(zl, sa, i, j, ZA, ZAi, ZAj); }
        sig_step<KB>(ZB, ZBi, ZBj, A4, A3, A2, a1i);
        { const int sb = (s + 4 < n) ? (s + 4) : (n - 1); zload(zl, sb, i, j, ZB, ZBi, ZBj); }
        sig_step<KB>(ZC, ZCi, ZCj, A4, A3, A2, a1i);
        { const int sc = (s + 5 < n) ? (s + 5) : (n - 1); zload(zl, sc, i, j, ZC, ZCi, ZCj); }
        s += 3;
    }
    const int rem = n - triples * 3;                  // 0 or 1 (n = 64 or 63)
    if (rem >= 1) sig_step<KB>(ZA, ZAi, ZAj, A4, A3, A2, a1i);
    if (rem >= 2) sig_step<KB>(ZB, ZBi, ZBj, A4, A3, A2, a1i);

    if (KB == 0) {
        if (lane < 8) o[lane] = pb[(size_t)t1 * D8 + lane] - pb[(size_t)t0 * D8 + lane];
        o[OFF2 + lane] = A2;
    }
    // transposed, fully-coalesced epilogue stores
#pragma unroll
    for (int kk = 0; kk < 4; ++kk) {
        o[OFF3 + (KB + kk) * 64 + lane] = A3[kk];
#pragma unroll
        for (int l = 0; l < 8; ++l)
            o[OFF4 + ((KB + kk) * 8 + l) * 64 + lane] = A4[kk][l];
    }
}

__global__ __launch_bounds__(128, 4) void sig_chunk_kernel(const float* __restrict__ path,
                                                           float* __restrict__ sigs) {
    __shared__ float4 zl4[130];                   // 64 steps x 8 floats (+pad)
    float* zl = (float*)zl4;

    const int wg   = blockIdx.x;                  // b*NCHUNK + c
    const int b    = wg >> 5;
    const int c    = wg & (NCHUNK - 1);
    const int tid  = threadIdx.x;
    const int w    = tid >> 6;
    const int lane = tid & 63;
    const int i    = lane >> 3;
    const int j    = lane & 7;
    const int t0   = c * CSTEPS;
    const int t1   = (t0 + CSTEPS < NSTEPS) ? (t0 + CSTEPS) : NSTEPS;
    const int n    = t1 - t0;                     // 64 or 63
    const float* __restrict__ pb = path + (size_t)b * LPATH * D8;

    // prologue: z[s][m] = p[t0+s+1][m] - p[t0+s][m], one float4 per thread
    if (tid * 4 < n * 8) {
        const float* src = pb + (size_t)t0 * D8 + tid * 4;
        float4 a  = *(const float4*)(src + 8);
        float4 bq = *(const float4*)(src);
        zl4[tid] = make_float4(a.x - bq.x, a.y - bq.y, a.z - bq.z, a.w - bq.w);
    }
    __syncthreads();

    float* __restrict__ o = sigs + (size_t)wg * SIGLEN;
    if (w == 0) chunk_body<0>(zl, pb, o, t0, t1, n, lane, i, j);
    else        chunk_body<4>(zl, pb, o, t0, t1, n, lane, i, j);
}

// ============================ Phase 2 ============================
// k-split Chen combine over transposed sigs; all big loads coalesced dwords.
// 1 block = 4 waves per group; wave w owns k rows {2w,2w+1}.

template<int NPER, bool CANON_OUT>
__global__ __launch_bounds__(256) void sig_combine_kernel(const float* __restrict__ in,
                                                          float* __restrict__ out) {
    const int grp  = blockIdx.x;
    const int tid  = threadIdx.x;
    const int w    = tid >> 6;
    const int lane = tid & 63;
    const int i    = lane >> 3;
    const int j    = lane & 7;
    const int k0   = 2 * w;
    const float* __restrict__ base = in + (size_t)grp * NPER * SIGLEN;

    float A4[2][8], a3[2], A1[8], A2, a1i;
    load8(base, A1);
    a1i = base[i];
    A2  = base[OFF2 + lane];
    a3[0] = base[OFF3 + k0 * 64 + lane];
    a3[1] = base[OFF3 + (k0 + 1) * 64 + lane];
#pragma unroll
    for (int kk = 0; kk < 2; ++kk)
#pragma unroll
        for (int l = 0; l < 8; ++l)
            A4[kk][l] = base[OFF4 + ((k0 + kk) * 8 + l) * 64 + lane];

#pragma unroll 2
    for (int s = 1; s < NPER; ++s) {
        const float* __restrict__ B = base + (size_t)s * SIGLEN;
        float B1[8];   load8(B, B1);
        const float b1i = B[i];
        const float b1j = B[j];
        const float b2t = B[OFF2 + lane];                    // coalesced
        const float b1k[2]  = { B[k0], B[k0 + 1] };
        const float b3k[2]  = { B[OFF3 + k0 * 64 + lane],    // coalesced
                                B[OFF3 + (k0 + 1) * 64 + lane] };
        const float b2jk[2] = { B[OFF2 + j * 8 + k0],
                                B[OFF2 + j * 8 + k0 + 1] };
        float b4r[2][8], b2r[2][8], b3r[2][8];
#pragma unroll
        for (int kk = 0; kk < 2; ++kk) {
#pragma unroll
            for (int l = 0; l < 8; ++l)
                b4r[kk][l] = B[OFF4 + ((k0 + kk) * 8 + l) * 64 + lane];  // coalesced
            load8(B + OFF2 + (k0 + kk) * 8, b2r[kk]);        // uniform
#pragma unroll
            for (int l = 0; l < 8; ++l)
                b3r[kk][l] = B[OFF3 + l * 64 + j * 8 + (k0 + kk)];       // bcast groups
        }
        // C4[i,j,k,l] = A4 + B4 + A3[k]*B1[l] + A2*B2[k,l] + A1[i]*B3[j,k,l]
#pragma unroll
        for (int kk = 0; kk < 2; ++kk) {
#pragma unroll
            for (int l = 0; l < 8; ++l) {
                float v = A4[kk][l] + b4r[kk][l];
                v = fmaf(a3[kk], B1[l], v);
                v = fmaf(A2,     b2r[kk][l], v);
                A4[kk][l] = fmaf(a1i, b3r[kk][l], v);
            }
        }
        // C3[i,j,k] = A3 + B3[i,j,k] + A2*B1[k] + A1[i]*B2[j,k]
        a3[0] = fmaf(a1i, b2jk[0], fmaf(A2, b1k[0], a3[0] + b3k[0]));
        a3[1] = fmaf(a1i, b2jk[1], fmaf(A2, b1k[1], a3[1] + b3k[1]));
        // C2, C1
        A2 = A2 + fmaf(a1i, b1j, b2t);
#pragma unroll
        for (int m = 0; m < 8; ++m) A1[m] += B1[m];
        a1i += b1i;
    }

    float* __restrict__ o = out + (size_t)grp * SIGLEN;
    if (w == 0) {
        if (lane < 8) o[lane] = A1[lane];
        o[OFF2 + lane] = A2;
    }
    if (CANON_OUT) {
        o[OFF3 + lane * 8 + k0]     = a3[0];
        o[OFF3 + lane * 8 + k0 + 1] = a3[1];
        store8(o + OFF4 + lane * 64 + k0 * 8,       A4[0]);
        store8(o + OFF4 + lane * 64 + (k0 + 1) * 8, A4[1]);
    } else {
        o[OFF3 + k0 * 64 + lane]       = a3[0];
        o[OFF3 + (k0 + 1) * 64 + lane] = a3[1];
#pragma unroll
        for (int kk = 0; kk < 2; ++kk)
#pragma unroll
            for (int l = 0; l < 8; ++l)
                o[OFF4 + ((k0 + kk) * 8 + l) * 64 + lane] = A4[kk][l];
    }
}

extern "C" void kernel_launch(void* const* d_in, const int* in_sizes, int n_in,
                              void* d_out, int out_size, void* d_ws, size_t ws_size,
                              hipStream_t stream) {
    const float* path = (const float*)d_in[0];
    float* out   = (float*)d_out;
    float* sigs  = (float*)d_ws;                                  // 64*32*4680 f32 = 38.3 MB
    float* gsigs = sigs + (size_t)NBATCH * NCHUNK * SIGLEN;       // 64*4*4680 f32 = 4.8 MB

    sig_chunk_kernel<<<NBATCH * NCHUNK, 128, 0, stream>>>(path, sigs);
    sig_combine_kernel<8, false><<<NBATCH * 4, 256, 0, stream>>>(sigs, gsigs);
    sig_combine_kernel<4, true><<<NBATCH, 256, 0, stream>>>(gsigs, out);
}

// Round 8
// 47.318 us; speedup vs baseline: 1.2356x; 1.1422x over previous
//
#include <hip/hip_runtime.h>

#define D8      8
#define LPATH   2048
#define NBATCH  64
#define NSTEPS  2047         // L-1 increments
#define NCHUNK  32
#define CSTEPS  64           // increments per chunk (last chunk: 63)
#define SIGLEN  4680         // 8 + 64 + 512 + 4096
#define OFF2    8
#define OFF3    72
#define OFF4    584
#define APITCH  40           // bf16 elems per row of A/Bt LDS (80B, 16B-aligned, gcd(5,8)=1 bank spread)

typedef float  f32x4 __attribute__((ext_vector_type(4)));
typedef short  s16x8 __attribute__((ext_vector_type(8)));

__device__ __forceinline__ void load8(const float* __restrict__ p, float* v) {
    float4 a = ((const float4*)p)[0];
    float4 b = ((const float4*)p)[1];
    v[0]=a.x; v[1]=a.y; v[2]=a.z; v[3]=a.w;
    v[4]=b.x; v[5]=b.y; v[6]=b.z; v[7]=b.w;
}
__device__ __forceinline__ void store8(float* __restrict__ p, const float* v) {
    ((float4*)p)[0] = make_float4(v[0],v[1],v[2],v[3]);
    ((float4*)p)[1] = make_float4(v[4],v[5],v[6],v[7]);
}
__device__ __forceinline__ unsigned int f2bf(float f) {   // RNE f32->bf16 bits
    unsigned int u = __builtin_bit_cast(unsigned int, f);
    u += 0x7FFFu + ((u >> 16) & 1u);
    return u >> 16;
}

// ============================ Phase 1 (MFMA) ============================
// One wave per chunk, 4 chunks per 256-thread block.
// A4 = [C3|C4](64x128) x [H3;H4](128x64) via 16x16x32 bf16 MFMA in 4 K-passes.
// Sequential part per step: A2/a1 recursion -> c3,c4 (per-lane (i,j)),
// h3 = z[k]*W_suffix[l], h4 = z[k]*z[l] (per-lane (k,l)=(i,j)); A3 in f32 VALU.
__global__ __launch_bounds__(256, 3) void sig_chunk_mfma(const float* __restrict__ path,
                                                         float* __restrict__ sigs) {
    __shared__ float          zl[4][CSTEPS * D8];     // 4 x 2 KB
    __shared__ unsigned short Al[4][64 * APITCH];     // 4 x 5 KB  (A: rows ij, cols k-pass)
    __shared__ unsigned short Bl[4][64 * APITCH];     // 4 x 5 KB  (Bt: rows kl, cols k-pass)

    const int w    = threadIdx.x >> 6;
    const int lane = threadIdx.x & 63;
    const int chunk = blockIdx.x * 4 + w;
    const int b    = chunk >> 5;
    const int c    = chunk & (NCHUNK - 1);
    const int t0   = c * CSTEPS;
    const int t1   = (t0 + CSTEPS < NSTEPS) ? (t0 + CSTEPS) : NSTEPS;
    const int n    = t1 - t0;                         // 64 or 63
    const int i    = lane >> 3;
    const int j    = lane & 7;
    const float* __restrict__ pb = path + (size_t)b * LPATH * D8;

    // ---- prologue: z rows into LDS (row lane), zero-fill missing steps ----
    {
        float4 z0, z1;
        if (lane < n) {
            const float* s0 = pb + (size_t)(t0 + lane) * D8;
            float4 a0 = ((const float4*)s0)[0], a1v = ((const float4*)s0)[1];
            float4 b0 = ((const float4*)(s0 + D8))[0], b1v = ((const float4*)(s0 + D8))[1];
            z0 = make_float4(b0.x - a0.x, b0.y - a0.y, b0.z - a0.z, b0.w - a0.w);
            z1 = make_float4(b1v.x - a1v.x, b1v.y - a1v.y, b1v.z - a1v.z, b1v.w - a1v.w);
        } else {
            z0 = make_float4(0.f, 0.f, 0.f, 0.f);
            z1 = z0;
        }
        ((float4*)(&zl[w][lane * D8]))[0] = z0;
        ((float4*)(&zl[w][lane * D8]))[1] = z1;
    }
    __syncthreads();   // wave-internal LDS visibility (cheap, once)

    const float Tj = pb[(size_t)t1 * D8 + j] - pb[(size_t)t0 * D8 + j];

    float A2 = 0.f, a1i = 0.f, Wl = Tj;
    float A3[8];
#pragma unroll
    for (int k = 0; k < 8; ++k) A3[k] = 0.f;
    f32x4 acc[4][4];
#pragma unroll
    for (int rt = 0; rt < 4; ++rt)
#pragma unroll
        for (int ct = 0; ct < 4; ++ct)
            acc[rt][ct] = (f32x4){0.f, 0.f, 0.f, 0.f};

    float* __restrict__ zw = &zl[w][0];
    unsigned short* __restrict__ Aw = &Al[w][0];
    unsigned short* __restrict__ Bw = &Bl[w][0];

    for (int pass = 0; pass < 4; ++pass) {
        const float* __restrict__ zp = zw + pass * 16 * D8;
        // ---- sequential 16 steps: build A (c3|c4) and Bt (h3|h4) bf16 tiles ----
#pragma unroll
        for (int bt = 0; bt < 2; ++bt) {
            unsigned int c3pk[4], c4pk[4], h3pk[4], h4pk[4];
#pragma unroll
            for (int e = 0; e < 8; ++e) {
                const int so = (bt * 8 + e) * D8;   // compile-time offset
                float4 za = *(const float4*)(zp + so);
                float4 zb = *(const float4*)(zp + so + 4);
                const float Z[8] = {za.x, za.y, za.z, za.w, zb.x, zb.y, zb.z, zb.w};
                const float Zi = zp[so + i];
                const float Zj = zp[so + j];

                const float p   = Zi * Zj;                                   // == h4
                const float uq  = a1i * Zj;
                const float c4v = fmaf(uq, 1.f/6.f, fmaf(p, 1.f/24.f, A2 * 0.5f));
                const float c3v = fmaf(uq, 0.5f,    fmaf(p, 1.f/6.f,  A2));
                Wl -= Zj;
                const float h3v = Zi * Wl;
#pragma unroll
                for (int k = 0; k < 8; ++k) A3[k] = fmaf(c3v, Z[k], A3[k]);
                A2 = A2 + fmaf(p, 0.5f, uq);
                a1i += Zi;

                const unsigned int bc3 = f2bf(c3v), bc4 = f2bf(c4v);
                const unsigned int bh3 = f2bf(h3v), bh4 = f2bf(p);
                if ((e & 1) == 0) {
                    c3pk[e >> 1] = bc3; c4pk[e >> 1] = bc4;
                    h3pk[e >> 1] = bh3; h4pk[e >> 1] = bh4;
                } else {
                    c3pk[e >> 1] |= bc3 << 16; c4pk[e >> 1] |= bc4 << 16;
                    h3pk[e >> 1] |= bh3 << 16; h4pk[e >> 1] |= bh4 << 16;
                }
            }
            // K-layout per pass: k 0..15 = c3/h3 (steps), k 16..31 = c4/h4
            *(uint4*)(Aw + lane * APITCH + bt * 8)      = make_uint4(c3pk[0], c3pk[1], c3pk[2], c3pk[3]);
            *(uint4*)(Aw + lane * APITCH + 16 + bt * 8) = make_uint4(c4pk[0], c4pk[1], c4pk[2], c4pk[3]);
            *(uint4*)(Bw + lane * APITCH + bt * 8)      = make_uint4(h3pk[0], h3pk[1], h3pk[2], h3pk[3]);
            *(uint4*)(Bw + lane * APITCH + 16 + bt * 8) = make_uint4(h4pk[0], h4pk[1], h4pk[2], h4pk[3]);
        }
        // ---- MFMA stage: 16 tiles x K=32 ----
        s16x8 af[4], bfr[4];
#pragma unroll
        for (int rt = 0; rt < 4; ++rt)
            af[rt] = *(const s16x8*)(Aw + (rt * 16 + (lane & 15)) * APITCH + (lane >> 4) * 8);
#pragma unroll
        for (int ct = 0; ct < 4; ++ct)
            bfr[ct] = *(const s16x8*)(Bw + (ct * 16 + (lane & 15)) * APITCH + (lane >> 4) * 8);
#pragma unroll
        for (int rt = 0; rt < 4; ++rt)
#pragma unroll
            for (int ct = 0; ct < 4; ++ct)
                acc[rt][ct] = __builtin_amdgcn_mfma_f32_16x16x32_bf16(af[rt], bfr[ct], acc[rt][ct], 0, 0, 0);
    }

    // ---- epilogue: canonical layout ----
    float* __restrict__ o = sigs + (size_t)chunk * SIGLEN;
    if (lane < 8) o[lane] = pb[(size_t)t1 * D8 + lane] - pb[(size_t)t0 * D8 + lane];
    o[OFF2 + lane] = A2;
    store8(o + OFF3 + lane * 8, A3);
    const int r0 = (lane >> 4) * 4;       // C/D: row=(lane>>4)*4+reg, col=lane&15 (verified)
    const int cl = lane & 15;
#pragma unroll
    for (int rt = 0; rt < 4; ++rt)
#pragma unroll
        for (int ct = 0; ct < 4; ++ct)
#pragma unroll
            for (int reg = 0; reg < 4; ++reg)
                o[OFF4 + (size_t)(rt * 16 + r0 + reg) * 64 + ct * 16 + cl] = acc[rt][ct][reg];
}

// ============================ Phase 2 ============================
// k-split Chen combine (canonical layout, r2/r3 known-good): 1 block (4 waves)
// per group; wave w owns k rows {2w,2w+1}; A1/A2/a1i replicated.
template<int NPER>
__global__ __launch_bounds__(256) void sig_combine_kernel(const float* __restrict__ in,
                                                          float* __restrict__ out) {
    const int grp  = blockIdx.x;
    const int tid  = threadIdx.x;
    const int w    = tid >> 6;
    const int lane = tid & 63;
    const int i    = lane >> 3;
    const int j    = lane & 7;
    const int k0   = 2 * w;
    const float* __restrict__ base = in + (size_t)grp * NPER * SIGLEN;

    float A4[2][8], a3[2], A1[8], A2, a1i;
    load8(base, A1);
    a1i = base[i];
    A2  = base[OFF2 + lane];
    {
        float2 v = *(const float2*)(base + OFF3 + lane * 8 + k0);
        a3[0] = v.x; a3[1] = v.y;
    }
    load8(base + OFF4 + lane * 64 + k0 * 8,       A4[0]);
    load8(base + OFF4 + lane * 64 + (k0 + 1) * 8, A4[1]);

#pragma unroll 2
    for (int s = 1; s < NPER; ++s) {
        const float* __restrict__ B = base + (size_t)s * SIGLEN;
        float B1[8];   load8(B, B1);
        const float b1i = B[i];
        const float b1j = B[j];
        const float b2t = B[OFF2 + lane];
        const float2 b1k  = *(const float2*)(B + k0);
        const float2 b3k  = *(const float2*)(B + OFF3 + lane * 8 + k0);
        const float2 b2jk = *(const float2*)(B + OFF2 + j * 8 + k0);
        float b4r[2][8], b2r[2][8], b3r[2][8];
#pragma unroll
        for (int kk = 0; kk < 2; ++kk) {
            load8(B + OFF4 + lane * 64 + (k0 + kk) * 8, b4r[kk]);
            load8(B + OFF2 + (k0 + kk) * 8,             b2r[kk]);
            load8(B + OFF3 + j * 64 + (k0 + kk) * 8,    b3r[kk]);
        }
#pragma unroll
        for (int kk = 0; kk < 2; ++kk) {
#pragma unroll
            for (int l = 0; l < 8; ++l) {
                float v = A4[kk][l] + b4r[kk][l];
                v = fmaf(a3[kk], B1[l], v);
                v = fmaf(A2,     b2r[kk][l], v);
                A4[kk][l] = fmaf(a1i, b3r[kk][l], v);
            }
        }
        a3[0] = fmaf(a1i, b2jk.x, fmaf(A2, b1k.x, a3[0] + b3k.x));
        a3[1] = fmaf(a1i, b2jk.y, fmaf(A2, b1k.y, a3[1] + b3k.y));
        A2 = A2 + fmaf(a1i, b1j, b2t);
#pragma unroll
        for (int m = 0; m < 8; ++m) A1[m] += B1[m];
        a1i += b1i;
    }

    float* __restrict__ o = out + (size_t)grp * SIGLEN;
    if (w == 0) {
        if (lane < 8) o[lane] = A1[lane];
        o[OFF2 + lane] = A2;
    }
    *(float2*)(o + OFF3 + lane * 8 + k0) = make_float2(a3[0], a3[1]);
    store8(o + OFF4 + lane * 64 + k0 * 8,       A4[0]);
    store8(o + OFF4 + lane * 64 + (k0 + 1) * 8, A4[1]);
}

extern "C" void kernel_launch(void* const* d_in, const int* in_sizes, int n_in,
                              void* d_out, int out_size, void* d_ws, size_t ws_size,
                              hipStream_t stream) {
    const float* path = (const float*)d_in[0];
    float* out   = (float*)d_out;
    float* sigs  = (float*)d_ws;                                  // 64*32*4680 f32 = 38.3 MB
    float* gsigs = sigs + (size_t)NBATCH * NCHUNK * SIGLEN;       // 64*4*4680 f32 = 4.8 MB

    sig_chunk_mfma<<<NBATCH * NCHUNK / 4, 256, 0, stream>>>(path, sigs);
    sig_combine_kernel<8><<<NBATCH * 4, 256, 0, stream>>>(sigs, gsigs);
    sig_combine_kernel<4><<<NBATCH, 256, 0, stream>>>(gsigs, out);
}